// Round 2
// baseline (149.299 us; speedup 1.0000x reference)
//
#include <hip/hip_runtime.h>

#define BATCH 4
#define SEQ   4096
#define EMB   1024
#define HD    64
#define NROW  (BATCH*SEQ)

typedef float f32x4  __attribute__((ext_vector_type(4)));
typedef short bf16x8 __attribute__((ext_vector_type(8)));
typedef short bf16x4 __attribute__((ext_vector_type(4)));

#define LOG2E 1.4426950408889634f

static __device__ __forceinline__ short f2bf(float f) {
  union { float f; unsigned u; } v; v.f = f;
  unsigned r = v.u + 0x7fffu + ((v.u >> 16) & 1u);
  return (short)(r >> 16);
}

// ---------------------------------------------------------------------------
// Wt[n][e] = W_{n/64}[e][n%64] as bf16. LDS-transpose, coalesced both sides.
// grid 48 = 3 mats x 16 e-tiles of 64.
// ---------------------------------------------------------------------------
__global__ __launch_bounds__(256) void wt_kernel(
    const float* __restrict__ Wq, const float* __restrict__ Wk,
    const float* __restrict__ Wv, short* __restrict__ Wt) {
  __shared__ float t[64][65];
  int bid = blockIdx.x;
  int mat = bid >> 4;
  int e0  = (bid & 15) * 64;
  const float* W = (mat == 0) ? Wq : (mat == 1) ? Wk : Wv;
  int c  = threadIdx.x & 63;
  int r0 = threadIdx.x >> 6;
#pragma unroll
  for (int i = 0; i < 16; ++i)
    t[i * 4 + r0][c] = W[(size_t)(e0 + i * 4 + r0) * HD + c];
  __syncthreads();
  int n  = threadIdx.x >> 2;
  int eb = (threadIdx.x & 3) * 16;
  short* dst = Wt + (size_t)(mat * 64 + n) * EMB + e0 + eb;
#pragma unroll
  for (int j = 0; j < 4; ++j) {
    bf16x4 v;
#pragma unroll
    for (int q = 0; q < 4; ++q) v[q] = f2bf(t[eb + j * 4 + q][n]);
    *(bf16x4*)(dst + j * 4) = v;
  }
}

// ---------------------------------------------------------------------------
// QKV projection, split-K x4: block = 16 rows x 192 cols; wave w covers
// K range [w*256,(w+1)*256). Combine via LDS f32 atomics. grid = 1024.
// ---------------------------------------------------------------------------
__global__ __launch_bounds__(256) void qkv_kernel(
    const float* __restrict__ X, const short* __restrict__ Wt,
    const float* __restrict__ bq, const float* __restrict__ bk, const float* __restrict__ bv,
    short* __restrict__ Qb, short* __restrict__ Kb, short* __restrict__ Vt) {
  __shared__ float lds_acc[12][4][64];   // 12 KB

  int tid  = threadIdx.x;
  int w    = tid >> 6;
  int lane = tid & 63;
  int g    = lane >> 4;
  int mi   = lane & 15;
  int rowbase = blockIdx.x * 16;
  const float* xrow = X + (size_t)(rowbase + mi) * EMB + w * 256;
  const short* wrow = Wt + w * 256 + 8 * g;

  f32x4 acc[12];
#pragma unroll
  for (int i = 0; i < 12; ++i) acc[i] = (f32x4){0.f, 0.f, 0.f, 0.f};

#pragma unroll
  for (int k0 = 0; k0 < 256; k0 += 32) {
    float4 xa = *(const float4*)(xrow + k0 + 8 * g);
    float4 xb = *(const float4*)(xrow + k0 + 8 * g + 4);
    bf16x8 af;
    af[0] = f2bf(xa.x); af[1] = f2bf(xa.y); af[2] = f2bf(xa.z); af[3] = f2bf(xa.w);
    af[4] = f2bf(xb.x); af[5] = f2bf(xb.y); af[6] = f2bf(xb.z); af[7] = f2bf(xb.w);
#pragma unroll
    for (int ct = 0; ct < 12; ++ct) {
      bf16x8 bfr = *(const bf16x8*)(wrow + (size_t)(ct * 16 + mi) * EMB + k0);
      acc[ct] = __builtin_amdgcn_mfma_f32_16x16x32_bf16(af, bfr, acc[ct], 0, 0, 0);
    }
  }

  // cross-wave combine
  if (w == 0) {
#pragma unroll
    for (int ct = 0; ct < 12; ++ct)
#pragma unroll
      for (int r = 0; r < 4; ++r) lds_acc[ct][r][lane] = acc[ct][r];
  }
  __syncthreads();
  if (w != 0) {
#pragma unroll
    for (int ct = 0; ct < 12; ++ct)
#pragma unroll
      for (int r = 0; r < 4; ++r)
        atomicAdd(&lds_acc[ct][r][lane], acc[ct][r]);
  }
  __syncthreads();

  // epilogue: Q,K rows (coalesced 8B stores); V transposed (8B chunks in s)
  {
    int row = tid >> 4;
    int c0  = (tid & 15) * 4;
    int x0  = (row >> 2) * 16;
#pragma unroll
    for (int mat = 0; mat < 2; ++mat) {
      const float* bp = mat ? bk : bq;
      bf16x4 v;
#pragma unroll
      for (int j = 0; j < 4; ++j) {
        int cc = c0 + j;
        v[j] = f2bf(lds_acc[mat * 4 + (c0 >> 4)][row & 3][x0 + (cc & 15)] + bp[cc]);
      }
      short* dst = (mat ? Kb : Qb) + (size_t)(rowbase + row) * HD + c0;
      *(bf16x4*)dst = v;
    }
  }
  {
    int col = tid & 63;
    int s0  = (tid >> 6) * 4;
    int b   = rowbase >> 12;
    int srow = rowbase & (SEQ - 1);
    float bias = bv[col];
    bf16x4 v;
#pragma unroll
    for (int r = 0; r < 4; ++r)
      v[r] = f2bf(lds_acc[8 + (col >> 4)][r][(s0 >> 2) * 16 + (col & 15)] + bias);
    *(bf16x4*)(Vt + ((size_t)(b * HD + col)) * SEQ + srow + s0) = v;
  }
}

// ---------------------------------------------------------------------------
// Flash attention, swapped layout (S^T = K*Q^T, O^T = V^T*P^T). Unchanged.
// ---------------------------------------------------------------------------
__global__ __launch_bounds__(256, 2) void attn_kernel(
    const short* __restrict__ Qb, const short* __restrict__ Kb,
    const short* __restrict__ Vt, float* __restrict__ out) {
  __shared__ float lds_o[4][64][16];   // [wave][h][q]
  __shared__ float lds_m[4][16];
  __shared__ float lds_l[4][16];
  __shared__ short p_lds[4][16][32];   // [wave][q][kv]

  int tid  = threadIdx.x;
  int w    = tid >> 6;
  int lane = tid & 63;
  int g    = lane >> 4;
  int qi   = lane & 15;
  int batch = blockIdx.x >> 7;
  int jj    = blockIdx.x & 127;

  for (int ph = 0; ph < 2; ++ph) {
    int t  = ph ? (255 - jj) : jj;
    int q0 = t * 16;
    int row = q0 + qi;

    const short* qptr = Qb + ((size_t)(batch * SEQ + row)) * HD + 8 * g;
    bf16x8 qf0 = *(const bf16x8*)(qptr);
    bf16x8 qf1 = *(const bf16x8*)(qptr + 32);

    int C  = t + 1;
    int c0 = (w * C) >> 2;
    int c1 = ((w + 1) * C) >> 2;

    float m = -INFINITY, lsum = 0.f;
    f32x4 o[4];
#pragma unroll
    for (int i = 0; i < 4; ++i) o[i] = (f32x4){0.f, 0.f, 0.f, 0.f};

    for (int c = c0; c < c1; c += 2) {
      int kv0 = c * 16;
      bool have1 = (c + 1 < c1);
      float s[2][4];
      {
        const short* kptr = Kb + ((size_t)(batch * SEQ + kv0 + qi)) * HD + 8 * g;
        bf16x8 kf0 = *(const bf16x8*)(kptr);
        bf16x8 kf1 = *(const bf16x8*)(kptr + 32);
        f32x4 z = (f32x4){0.f, 0.f, 0.f, 0.f};
        z = __builtin_amdgcn_mfma_f32_16x16x32_bf16(kf0, qf0, z, 0, 0, 0);
        z = __builtin_amdgcn_mfma_f32_16x16x32_bf16(kf1, qf1, z, 0, 0, 0);
#pragma unroll
        for (int r = 0; r < 4; ++r) {
          int col = kv0 + 4 * g + r;
          s[0][r] = (col <= row) ? z[r] * 0.125f : -INFINITY;
        }
      }
      if (have1) {
        const short* kptr = Kb + ((size_t)(batch * SEQ + kv0 + 16 + qi)) * HD + 8 * g;
        bf16x8 kf0 = *(const bf16x8*)(kptr);
        bf16x8 kf1 = *(const bf16x8*)(kptr + 32);
        f32x4 z = (f32x4){0.f, 0.f, 0.f, 0.f};
        z = __builtin_amdgcn_mfma_f32_16x16x32_bf16(kf0, qf0, z, 0, 0, 0);
        z = __builtin_amdgcn_mfma_f32_16x16x32_bf16(kf1, qf1, z, 0, 0, 0);
#pragma unroll
        for (int r = 0; r < 4; ++r) {
          int col = kv0 + 16 + 4 * g + r;
          s[1][r] = (col <= row) ? z[r] * 0.125f : -INFINITY;
        }
      } else {
#pragma unroll
        for (int r = 0; r < 4; ++r) s[1][r] = -INFINITY;
      }

      float pmax = fmaxf(fmaxf(fmaxf(s[0][0], s[0][1]), fmaxf(s[0][2], s[0][3])),
                         fmaxf(fmaxf(s[1][0], s[1][1]), fmaxf(s[1][2], s[1][3])));
      pmax = fmaxf(pmax, __shfl_xor(pmax, 16));
      pmax = fmaxf(pmax, __shfl_xor(pmax, 32));
      float mnew  = fmaxf(m, pmax);
      float alpha = exp2f((m - mnew) * LOG2E);

      float sum = 0.f;
      unsigned pw[2][2];
#pragma unroll
      for (int f = 0; f < 2; ++f) {
        float p0 = exp2f((s[f][0] - mnew) * LOG2E);
        float p1 = exp2f((s[f][1] - mnew) * LOG2E);
        float p2 = exp2f((s[f][2] - mnew) * LOG2E);
        float p3 = exp2f((s[f][3] - mnew) * LOG2E);
        sum += p0 + p1 + p2 + p3;
        pw[f][0] = ((unsigned)(unsigned short)f2bf(p1) << 16) | (unsigned short)f2bf(p0);
        pw[f][1] = ((unsigned)(unsigned short)f2bf(p3) << 16) | (unsigned short)f2bf(p2);
      }
      sum += __shfl_xor(sum, 16);
      sum += __shfl_xor(sum, 32);
      lsum = lsum * alpha + sum;
      m = mnew;
#pragma unroll
      for (int i = 0; i < 4; ++i) {
        o[i][0] *= alpha; o[i][1] *= alpha; o[i][2] *= alpha; o[i][3] *= alpha;
      }

      *(uint2*)(&p_lds[w][qi][4 * g])      = make_uint2(pw[0][0], pw[0][1]);
      *(uint2*)(&p_lds[w][qi][16 + 4 * g]) = make_uint2(pw[1][0], pw[1][1]);

      bf16x8 pf = *(const bf16x8*)(&p_lds[w][qi][8 * g]);
#pragma unroll
      for (int ht = 0; ht < 4; ++ht) {
        const short* vptr = Vt + ((size_t)(batch * HD + ht * 16 + qi)) * SEQ + kv0 + 8 * g;
        bf16x8 vf = *(const bf16x8*)(vptr);
        o[ht] = __builtin_amdgcn_mfma_f32_16x16x32_bf16(vf, pf, o[ht], 0, 0, 0);
      }
    }

#pragma unroll
    for (int ht = 0; ht < 4; ++ht)
#pragma unroll
      for (int r = 0; r < 4; ++r)
        lds_o[w][ht * 16 + 4 * g + r][qi] = o[ht][r];
    if (lane < 16) { lds_m[w][lane] = m; lds_l[w][lane] = lsum; }
    __syncthreads();

    {
      int q  = tid & 15;
      int hb = (tid >> 4) * 4;
      float m0 = lds_m[0][q], m1 = lds_m[1][q], m2 = lds_m[2][q], m3 = lds_m[3][q];
      float mm = fmaxf(fmaxf(m0, m1), fmaxf(m2, m3));
      float e0 = exp2f((m0 - mm) * LOG2E);
      float e1 = exp2f((m1 - mm) * LOG2E);
      float e2 = exp2f((m2 - mm) * LOG2E);
      float e3 = exp2f((m3 - mm) * LOG2E);
      float denom = lds_l[0][q] * e0 + lds_l[1][q] * e1 + lds_l[2][q] * e2 + lds_l[3][q] * e3;
      float inv = 1.f / denom;
      f32x4 res;
#pragma unroll
      for (int i = 0; i < 4; ++i) {
        res[i] = (e0 * lds_o[0][hb + i][q] + e1 * lds_o[1][hb + i][q] +
                  e2 * lds_o[2][hb + i][q] + e3 * lds_o[3][hb + i][q]) * inv;
      }
      *(f32x4*)(out + ((size_t)(batch * SEQ + q0 + q)) * HD + hb) = res;
    }
    __syncthreads();
  }
}

// ---------------------------------------------------------------------------
extern "C" void kernel_launch(void* const* d_in, const int* in_sizes, int n_in,
                              void* d_out, int out_size, void* d_ws, size_t ws_size,
                              hipStream_t stream) {
  const float* X  = (const float*)d_in[0];
  const float* Wq = (const float*)d_in[1];
  const float* bq = (const float*)d_in[2];
  const float* Wk = (const float*)d_in[3];
  const float* bk = (const float*)d_in[4];
  const float* Wv = (const float*)d_in[5];
  const float* bv = (const float*)d_in[6];
  float* out = (float*)d_out;

  char* ws = (char*)d_ws;
  const size_t SZ = (size_t)NROW * HD * 2;   // 2 MB per tensor (bf16)
  short* Qb = (short*)(ws);
  short* Kb = (short*)(ws + SZ);
  short* Vt = (short*)(ws + 2 * SZ);
  short* Wt = (short*)(ws + 3 * SZ);         // 384 KB

  wt_kernel<<<48, 256, 0, stream>>>(Wq, Wk, Wv, Wt);
  qkv_kernel<<<NROW / 16, 256, 0, stream>>>(X, Wt, bq, bk, bv, Qb, Kb, Vt);
  attn_kernel<<<BATCH * 128, 256, 0, stream>>>(Qb, Kb, Vt, out);
}

// Round 3
// 78.445 us; speedup vs baseline: 1.9032x; 1.9032x over previous
//
#include <hip/hip_runtime.h>

#define BATCH 4
#define SEQ   4096
#define EMB   1024
#define HD    64
#define NROW  (BATCH*SEQ)

typedef float f32x4  __attribute__((ext_vector_type(4)));
typedef short bf16x8 __attribute__((ext_vector_type(8)));
typedef short bf16x4 __attribute__((ext_vector_type(4)));

#define LOG2E 1.4426950408889634f

static __device__ __forceinline__ short f2bf(float f) {
  union { float f; unsigned u; } v; v.f = f;
  unsigned r = v.u + 0x7fffu + ((v.u >> 16) & 1u);
  return (short)(r >> 16);
}

// ---------------------------------------------------------------------------
// Wtf: fragment-contiguous B layout. For ct in [0,12), ks in [0,32):
// chunk of 64 lanes x 8 bf16: lane (g*16+mi) holds W_mat[e=32*ks+8g .. +8][h],
// h = (ct%4)*16+mi, mat = ct/4. Index: ((ct*32+ks)*64 + lane)*8 shorts.
// ---------------------------------------------------------------------------
__global__ __launch_bounds__(256) void wt_kernel(
    const float* __restrict__ Wq, const float* __restrict__ Wk,
    const float* __restrict__ Wv, short* __restrict__ Wtf) {
  __shared__ float t[64][65];
  int bid = blockIdx.x;
  int mat = bid >> 4;
  int et  = bid & 15;          // e-tile of 64
  int e0  = et * 64;
  const float* W = (mat == 0) ? Wq : (mat == 1) ? Wk : Wv;
  int c  = threadIdx.x & 63;
  int r0 = threadIdx.x >> 6;
#pragma unroll
  for (int i = 0; i < 16; ++i)
    t[i * 4 + r0][c] = W[(size_t)(e0 + i * 4 + r0) * HD + c];
  __syncthreads();
#pragma unroll
  for (int half = 0; half < 2; ++half) {
    int cid  = half * 256 + threadIdx.x;   // 0..511
    int ct4  = cid >> 7;                   // 0..3
    int ksl  = (cid >> 6) & 1;             // 0..1
    int lane = cid & 63;
    int g    = lane >> 4;
    int mi   = lane & 15;
    int ct   = mat * 4 + ct4;
    int ks   = et * 2 + ksl;
    bf16x8 v;
#pragma unroll
    for (int j = 0; j < 8; ++j)
      v[j] = f2bf(t[ksl * 32 + 8 * g + j][ct4 * 16 + mi]);
    *(bf16x8*)(Wtf + ((size_t)(ct * 32 + ks) * 64 + lane) * 8) = v;
  }
}

// ---------------------------------------------------------------------------
// QKV projection: BM=32 rows/block, split-K x2 across waves.
// wave w: rowset rs=w&1 (rows 16rs..16rs+15), K-half h=w>>1 ([512h,512h+512)).
// X staged to LDS as bf16 (double-buffered); B direct from Wtf (contiguous).
// grid = 512 (2 blocks/CU).
// ---------------------------------------------------------------------------
__global__ __launch_bounds__(256) void qkv_kernel(
    const float* __restrict__ X, const short* __restrict__ Wtf,
    const float* __restrict__ bq, const float* __restrict__ bk, const float* __restrict__ bv,
    short* __restrict__ Qb, short* __restrict__ Kb, short* __restrict__ Vf) {
  __shared__ __align__(16) short xs[2][2][32][32];   // [buf][khalf][row][k] 8 KB
  __shared__ float part[2][12][4][64];               // [rowset][ct][reg][lane] 24 KB

  int tid  = threadIdx.x;
  int w    = tid >> 6;
  int lane = tid & 63;
  int g    = lane >> 4;
  int mi   = lane & 15;
  int rs   = w & 1;
  int h    = w >> 1;
  int rowbase = blockIdx.x * 32;

  // staging role: thread covers row sr, 16B chunk sc, both K-halves
  int sr = tid >> 3;
  int sc = tid & 7;
  const float* xsrc = X + (size_t)(rowbase + sr) * EMB + sc * 4;

  f32x4 acc[12];
#pragma unroll
  for (int i = 0; i < 12; ++i) acc[i] = (f32x4){0.f, 0.f, 0.f, 0.f};

  // prologue: stage ks=0 into buf 0
  {
    float4 xa = *(const float4*)(xsrc);
    float4 xb = *(const float4*)(xsrc + 512);
    bf16x4 va, vb;
    va[0] = f2bf(xa.x); va[1] = f2bf(xa.y); va[2] = f2bf(xa.z); va[3] = f2bf(xa.w);
    vb[0] = f2bf(xb.x); vb[1] = f2bf(xb.y); vb[2] = f2bf(xb.z); vb[3] = f2bf(xb.w);
    *(bf16x4*)(&xs[0][0][sr][sc * 4]) = va;
    *(bf16x4*)(&xs[0][1][sr][sc * 4]) = vb;
  }
  __syncthreads();

  const short* wp = Wtf + (size_t)(h * 16) * 512 + lane * 8;

#pragma unroll 2
  for (int ks = 0; ks < 16; ++ks) {
    int buf = ks & 1;
    float4 xa, xb;
    if (ks < 15) {                       // issue next-tile loads EARLY
      xa = *(const float4*)(xsrc + (ks + 1) * 32);
      xb = *(const float4*)(xsrc + (ks + 1) * 32 + 512);
    }
    bf16x8 af = *(const bf16x8*)(&xs[buf][h][rs * 16 + mi][g * 8]);
    const short* wk = wp + ks * 512;
#pragma unroll
    for (int ct = 0; ct < 12; ++ct) {
      bf16x8 bfr = *(const bf16x8*)(wk + (size_t)ct * 16384);
      acc[ct] = __builtin_amdgcn_mfma_f32_16x16x32_bf16(af, bfr, acc[ct], 0, 0, 0);
    }
    if (ks < 15) {                       // convert + write to other buffer
      bf16x4 va, vb;
      va[0] = f2bf(xa.x); va[1] = f2bf(xa.y); va[2] = f2bf(xa.z); va[3] = f2bf(xa.w);
      vb[0] = f2bf(xb.x); vb[1] = f2bf(xb.y); vb[2] = f2bf(xb.z); vb[3] = f2bf(xb.w);
      *(bf16x4*)(&xs[buf ^ 1][0][sr][sc * 4]) = va;
      *(bf16x4*)(&xs[buf ^ 1][1][sr][sc * 4]) = vb;
    }
    __syncthreads();
  }

  // combine K-halves: D element (row 16rs+4g+r, col ct*16+mi) at part[rs][ct][r][g*16+mi]
  if (h == 1) {
#pragma unroll
    for (int ct = 0; ct < 12; ++ct)
#pragma unroll
      for (int r = 0; r < 4; ++r) part[rs][ct][r][lane] = acc[ct][r];
  }
  __syncthreads();
  if (h == 0) {
#pragma unroll
    for (int ct = 0; ct < 12; ++ct)
#pragma unroll
      for (int r = 0; r < 4; ++r) part[rs][ct][r][lane] += acc[ct][r];
  }
  __syncthreads();

  // coalesced stores: Q,K row-major
  {
    int row = tid >> 3;
    int c0  = (tid & 7) * 8;
    int rs2 = row >> 4, rr = row & 15, gg = rr >> 2, r2 = rr & 3;
    bf16x8 vq, vk;
#pragma unroll
    for (int j = 0; j < 8; ++j) {
      int col = c0 + j;
      vq[j] = f2bf(part[rs2][col >> 4][r2][gg * 16 + (col & 15)] + bq[col]);
      vk[j] = f2bf(part[rs2][4 + (col >> 4)][r2][gg * 16 + (col & 15)] + bk[col]);
    }
    *(bf16x8*)(Qb + (size_t)(rowbase + row) * HD + c0) = vq;
    *(bf16x8*)(Kb + (size_t)(rowbase + row) * HD + c0) = vk;
  }
  // Vf fragment-contiguous: per (b, c32, ht) 512 shorts, lane g*16+mi holds 8 kv
  {
    int b   = rowbase >> 12;
    int c32 = (rowbase & (SEQ - 1)) >> 5;
    int gv  = tid >> 6;
    int hh  = tid & 63;
    int ht  = hh >> 4, mv = hh & 15;
    float bias = bv[hh];
    bf16x8 vv;
#pragma unroll
    for (int p = 0; p < 8; ++p) {
      int row = gv * 8 + p;
      int rs2 = row >> 4, rr = row & 15, gg = rr >> 2, r2 = rr & 3;
      vv[p] = f2bf(part[rs2][8 + ht][r2][gg * 16 + mv] + bias);
    }
    *(bf16x8*)(Vf + ((size_t)((b * 128 + c32) * 4 + ht)) * 512 + (gv * 16 + mv) * 8) = vv;
  }
}

// ---------------------------------------------------------------------------
// Flash attention, swapped layout. V now loaded from fragment-contiguous Vf.
// ---------------------------------------------------------------------------
__global__ __launch_bounds__(256, 2) void attn_kernel(
    const short* __restrict__ Qb, const short* __restrict__ Kb,
    const short* __restrict__ Vf, float* __restrict__ out) {
  __shared__ float lds_o[4][64][16];
  __shared__ float lds_m[4][16];
  __shared__ float lds_l[4][16];
  __shared__ __align__(16) short p_lds[4][16][32];

  int tid  = threadIdx.x;
  int w    = tid >> 6;
  int lane = tid & 63;
  int g    = lane >> 4;
  int qi   = lane & 15;
  int batch = blockIdx.x >> 7;
  int jj    = blockIdx.x & 127;

  const short* vbase = Vf + (size_t)batch * 128 * 4 * 512;

  for (int ph = 0; ph < 2; ++ph) {
    int t  = ph ? (255 - jj) : jj;
    int q0 = t * 16;
    int row = q0 + qi;

    const short* qptr = Qb + ((size_t)(batch * SEQ + row)) * HD + 8 * g;
    bf16x8 qf0 = *(const bf16x8*)(qptr);
    bf16x8 qf1 = *(const bf16x8*)(qptr + 32);

    int C  = t + 1;
    int C2 = (C + 1) >> 1;                 // 32-kv blocks
    int b0 = (w * C2) >> 2;
    int b1 = ((w + 1) * C2) >> 2;
    int c0 = b0 * 2;
    int c1 = 2 * b1; if (c1 > C) c1 = C;   // in 16-chunks, c0 always even

    float m = -INFINITY, lsum = 0.f;
    f32x4 o[4];
#pragma unroll
    for (int i = 0; i < 4; ++i) o[i] = (f32x4){0.f, 0.f, 0.f, 0.f};

    for (int c = c0; c < c1; c += 2) {
      int kv0 = c * 16;
      bool have1 = (c + 1 < c1);
      float s[2][4];
      {
        const short* kptr = Kb + ((size_t)(batch * SEQ + kv0 + qi)) * HD + 8 * g;
        bf16x8 kf0 = *(const bf16x8*)(kptr);
        bf16x8 kf1 = *(const bf16x8*)(kptr + 32);
        f32x4 z = (f32x4){0.f, 0.f, 0.f, 0.f};
        z = __builtin_amdgcn_mfma_f32_16x16x32_bf16(kf0, qf0, z, 0, 0, 0);
        z = __builtin_amdgcn_mfma_f32_16x16x32_bf16(kf1, qf1, z, 0, 0, 0);
#pragma unroll
        for (int r = 0; r < 4; ++r) {
          int col = kv0 + 4 * g + r;
          s[0][r] = (col <= row) ? z[r] * 0.125f : -INFINITY;
        }
      }
      if (have1) {
        const short* kptr = Kb + ((size_t)(batch * SEQ + kv0 + 16 + qi)) * HD + 8 * g;
        bf16x8 kf0 = *(const bf16x8*)(kptr);
        bf16x8 kf1 = *(const bf16x8*)(kptr + 32);
        f32x4 z = (f32x4){0.f, 0.f, 0.f, 0.f};
        z = __builtin_amdgcn_mfma_f32_16x16x32_bf16(kf0, qf0, z, 0, 0, 0);
        z = __builtin_amdgcn_mfma_f32_16x16x32_bf16(kf1, qf1, z, 0, 0, 0);
#pragma unroll
        for (int r = 0; r < 4; ++r) {
          int col = kv0 + 16 + 4 * g + r;
          s[1][r] = (col <= row) ? z[r] * 0.125f : -INFINITY;
        }
      } else {
#pragma unroll
        for (int r = 0; r < 4; ++r) s[1][r] = -INFINITY;
      }

      float pmax = fmaxf(fmaxf(fmaxf(s[0][0], s[0][1]), fmaxf(s[0][2], s[0][3])),
                         fmaxf(fmaxf(s[1][0], s[1][1]), fmaxf(s[1][2], s[1][3])));
      pmax = fmaxf(pmax, __shfl_xor(pmax, 16));
      pmax = fmaxf(pmax, __shfl_xor(pmax, 32));
      float mnew  = fmaxf(m, pmax);
      float alpha = exp2f((m - mnew) * LOG2E);

      float sum = 0.f;
      unsigned pw[2][2];
#pragma unroll
      for (int f = 0; f < 2; ++f) {
        float p0 = exp2f((s[f][0] - mnew) * LOG2E);
        float p1 = exp2f((s[f][1] - mnew) * LOG2E);
        float p2 = exp2f((s[f][2] - mnew) * LOG2E);
        float p3 = exp2f((s[f][3] - mnew) * LOG2E);
        sum += p0 + p1 + p2 + p3;
        pw[f][0] = ((unsigned)(unsigned short)f2bf(p1) << 16) | (unsigned short)f2bf(p0);
        pw[f][1] = ((unsigned)(unsigned short)f2bf(p3) << 16) | (unsigned short)f2bf(p2);
      }
      sum += __shfl_xor(sum, 16);
      sum += __shfl_xor(sum, 32);
      lsum = lsum * alpha + sum;
      m = mnew;
#pragma unroll
      for (int i = 0; i < 4; ++i) {
        o[i][0] *= alpha; o[i][1] *= alpha; o[i][2] *= alpha; o[i][3] *= alpha;
      }

      *(uint2*)(&p_lds[w][qi][4 * g])      = make_uint2(pw[0][0], pw[0][1]);
      *(uint2*)(&p_lds[w][qi][16 + 4 * g]) = make_uint2(pw[1][0], pw[1][1]);

      bf16x8 pf = *(const bf16x8*)(&p_lds[w][qi][8 * g]);
      const short* vp = vbase + ((size_t)(c >> 1) * 4) * 512 + lane * 8;
#pragma unroll
      for (int ht = 0; ht < 4; ++ht) {
        bf16x8 vf = *(const bf16x8*)(vp + ht * 512);
        o[ht] = __builtin_amdgcn_mfma_f32_16x16x32_bf16(vf, pf, o[ht], 0, 0, 0);
      }
    }

#pragma unroll
    for (int ht = 0; ht < 4; ++ht)
#pragma unroll
      for (int r = 0; r < 4; ++r)
        lds_o[w][ht * 16 + 4 * g + r][qi] = o[ht][r];
    if (lane < 16) { lds_m[w][lane] = m; lds_l[w][lane] = lsum; }
    __syncthreads();

    {
      int q  = tid & 15;
      int hb = (tid >> 4) * 4;
      float m0 = lds_m[0][q], m1 = lds_m[1][q], m2 = lds_m[2][q], m3 = lds_m[3][q];
      float mm = fmaxf(fmaxf(m0, m1), fmaxf(m2, m3));
      float e0 = exp2f((m0 - mm) * LOG2E);
      float e1 = exp2f((m1 - mm) * LOG2E);
      float e2 = exp2f((m2 - mm) * LOG2E);
      float e3 = exp2f((m3 - mm) * LOG2E);
      float denom = lds_l[0][q] * e0 + lds_l[1][q] * e1 + lds_l[2][q] * e2 + lds_l[3][q] * e3;
      float inv = 1.f / denom;
      f32x4 res;
#pragma unroll
      for (int i = 0; i < 4; ++i) {
        res[i] = (e0 * lds_o[0][hb + i][q] + e1 * lds_o[1][hb + i][q] +
                  e2 * lds_o[2][hb + i][q] + e3 * lds_o[3][hb + i][q]) * inv;
      }
      *(f32x4*)(out + ((size_t)(batch * SEQ + q0 + q)) * HD + hb) = res;
    }
    __syncthreads();
  }
}

// ---------------------------------------------------------------------------
extern "C" void kernel_launch(void* const* d_in, const int* in_sizes, int n_in,
                              void* d_out, int out_size, void* d_ws, size_t ws_size,
                              hipStream_t stream) {
  const float* X  = (const float*)d_in[0];
  const float* Wq = (const float*)d_in[1];
  const float* bq = (const float*)d_in[2];
  const float* Wk = (const float*)d_in[3];
  const float* bk = (const float*)d_in[4];
  const float* Wv = (const float*)d_in[5];
  const float* bv = (const float*)d_in[6];
  float* out = (float*)d_out;

  char* ws = (char*)d_ws;
  const size_t SZ = (size_t)NROW * HD * 2;   // 2 MB per tensor (bf16)
  short* Qb  = (short*)(ws);
  short* Kb  = (short*)(ws + SZ);
  short* Vf  = (short*)(ws + 2 * SZ);
  short* Wtf = (short*)(ws + 3 * SZ);        // 384 KB

  wt_kernel<<<48, 256, 0, stream>>>(Wq, Wk, Wv, Wtf);
  qkv_kernel<<<NROW / 32, 256, 0, stream>>>(X, Wtf, bq, bk, bv, Qb, Kb, Vf);
  attn_kernel<<<BATCH * 128, 256, 0, stream>>>(Qb, Kb, Vf, out);
}